// Round 3
// baseline (453.802 us; speedup 1.0000x reference)
//
#include <hip/hip_runtime.h>
#include <hip/hip_bf16.h>
#include <cmath>

// Problem constants (fixed by setup_inputs)
#define B    2048
#define NH   512
#define NC   316
#define TPC  317
#define ROWLEN (NC * TPC)   // 100172

// d_out layout (flat float32, return-order concat)
#define OFF_LOSS    ((size_t)0)
#define OFF_TGT     ((size_t)1)
#define OFF_TOPP    ((size_t)(1 + B))
#define OFF_BOTP    (OFF_TOPP + (size_t)B * NC)
#define OFF_TIDX    (OFF_BOTP + (size_t)B * TPC)
#define OFF_BIDX    (OFF_TIDX + (size_t)B)
#define OFF_RIDX    (OFF_BIDX + (size_t)B)
#define OFF_PREDS   (OFF_RIDX + (size_t)B)

// ---------------- k_top: [B,NH] x [NH,NC] + softmax/argmax ----------------
#define K1_SB 8

__global__ __launch_bounds__(320) void k_top(const float* __restrict__ X,
                                             const float* __restrict__ Wt,
                                             const float* __restrict__ bt,
                                             float* __restrict__ out) {
    __shared__ float xs[K1_SB][NH];   // 16 KB
    __shared__ float lg[K1_SB][NC];   // ~10 KB
    const int tid = threadIdx.x;
    const int b0 = blockIdx.x * K1_SB;

    for (int idx = tid; idx < K1_SB * NH; idx += 320) {
        xs[idx >> 9][idx & (NH - 1)] = X[(size_t)(b0 + (idx >> 9)) * NH + (idx & (NH - 1))];
    }
    __syncthreads();

    if (tid < NC) {
        float acc[K1_SB];
        #pragma unroll
        for (int s = 0; s < K1_SB; ++s) acc[s] = 0.f;
        #pragma unroll 2
        for (int k = 0; k < NH; k += 4) {
            const float w0 = Wt[(k + 0) * NC + tid];
            const float w1 = Wt[(k + 1) * NC + tid];
            const float w2 = Wt[(k + 2) * NC + tid];
            const float w3 = Wt[(k + 3) * NC + tid];
            #pragma unroll
            for (int s = 0; s < K1_SB; ++s) {
                const float4 x4 = *(const float4*)&xs[s][k];
                acc[s] += x4.x * w0 + x4.y * w1 + x4.z * w2 + x4.w * w3;
            }
        }
        const float bbv = bt[tid];
        #pragma unroll
        for (int s = 0; s < K1_SB; ++s) lg[s][tid] = acc[s] + bbv;
    }
    __syncthreads();

    const int wave = tid >> 6, lane = tid & 63;
    float* __restrict__ top_probs = out + OFF_TOPP;
    float* __restrict__ top_indx  = out + OFF_TIDX;

    for (int s = wave; s < K1_SB; s += 5) {
        const int b = b0 + s;
        float m = -INFINITY; int mi = 0;
        for (int c = lane; c < NC; c += 64) {
            float v = lg[s][c];
            if (v > m) { m = v; mi = c; }
        }
        for (int off = 32; off > 0; off >>= 1) {
            float om = __shfl_xor(m, off);
            int omi  = __shfl_xor(mi, off);
            if (om > m || (om == m && omi < mi)) { m = om; mi = omi; }
        }
        float sum = 0.f;
        for (int c = lane; c < NC; c += 64) sum += expf(lg[s][c] - m);
        for (int off = 32; off > 0; off >>= 1) sum += __shfl_xor(sum, off);
        const float inv = 1.0f / sum;
        for (int c = lane; c < NC; c += 64)
            top_probs[(size_t)b * NC + c] = expf(lg[s][c] - m) * inv;
        if (lane == 0) top_indx[b] = (float)mi;
    }
}

// ------------- k_blogits: partial bottom logits, grid (NC, KCH) -------------
#define KCH     8
#define KLEN    (NH / KCH)    // 64
#define SG      8
#define SCR_PAD 320

__global__ __launch_bounds__(320) void k_blogits(const float* __restrict__ X,
                                                 const int* __restrict__ labels,
                                                 const float* __restrict__ Wb,
                                                 float* __restrict__ scratch) {
    __shared__ int   list[B];          // 8 KB
    __shared__ float xs[SG][KLEN];     // 2 KB
    __shared__ int   cnt;

    const int tid = threadIdx.x;
    const int c   = blockIdx.x;
    const int kc  = blockIdx.y;
    if (tid == 0) cnt = 0;
    __syncthreads();

    for (int i = tid; i < B; i += 320) {
        int lab = labels[i];
        if (lab / TPC == c) list[atomicAdd(&cnt, 1)] = i;
    }
    __syncthreads();
    const int n = cnt;
    if (n == 0) return;

    const float* __restrict__ Wc = Wb + (size_t)c * NH * TPC + (size_t)kc * KLEN * TPC;
    const float* __restrict__ Xc = X + kc * KLEN;

    for (int start = 0; start < n; start += SG) {
        const int ns = min(SG, n - start);
        __syncthreads();
        for (int idx = tid; idx < ns * KLEN; idx += 320) {
            xs[idx >> 6][idx & (KLEN - 1)] =
                Xc[(size_t)list[start + (idx >> 6)] * NH + (idx & (KLEN - 1))];
        }
        __syncthreads();

        if (tid < TPC) {
            float acc[SG];
            #pragma unroll
            for (int s = 0; s < SG; ++s) acc[s] = 0.f;
            #pragma unroll 2
            for (int k = 0; k < KLEN; k += 4) {
                const float w0 = Wc[(size_t)(k + 0) * TPC + tid];
                const float w1 = Wc[(size_t)(k + 1) * TPC + tid];
                const float w2 = Wc[(size_t)(k + 2) * TPC + tid];
                const float w3 = Wc[(size_t)(k + 3) * TPC + tid];
                #pragma unroll
                for (int s = 0; s < SG; ++s) {
                    const float4 x4 = *(const float4*)&xs[s][k];
                    acc[s] += x4.x * w0 + x4.y * w1 + x4.z * w2 + x4.w * w3;
                }
            }
            for (int s = 0; s < ns; ++s)
                scratch[((size_t)list[start + s] * KCH + kc) * SCR_PAD + tid] = acc[s];
        }
    }
}

// ------------- k_bfinal: reduce partials + bias, softmax, outputs -------------
__global__ __launch_bounds__(256) void k_bfinal(const int* __restrict__ labels,
                                                const float* __restrict__ bbias,
                                                const float* __restrict__ scratch,
                                                float* __restrict__ out) {
    const int tid  = threadIdx.x;
    const int lane = tid & 63;
    const int b    = blockIdx.x * 4 + (tid >> 6);

    const int lab = labels[b];
    const int c   = lab / TPC;
    const int pb  = lab - c * TPC;

    float lgv[5];
    #pragma unroll
    for (int i = 0; i < 5; ++i) {
        const int t = lane + 64 * i;
        float v = -INFINITY;
        if (t < TPC) {
            v = bbias[(size_t)c * TPC + t];
            #pragma unroll
            for (int kc = 0; kc < KCH; ++kc)
                v += scratch[((size_t)b * KCH + kc) * SCR_PAD + t];
        }
        lgv[i] = v;
    }

    float m = -INFINITY; int mi = 0;
    #pragma unroll
    for (int i = 0; i < 5; ++i) {
        const int t = lane + 64 * i;
        if (lgv[i] > m) { m = lgv[i]; mi = t; }
    }
    for (int off = 32; off > 0; off >>= 1) {
        float om = __shfl_xor(m, off);
        int omi  = __shfl_xor(mi, off);
        if (om > m || (om == m && omi < mi)) { m = om; mi = omi; }
    }

    float pv[5];
    float sum = 0.f;
    #pragma unroll
    for (int i = 0; i < 5; ++i) {
        const int t = lane + 64 * i;
        pv[i] = (t < TPC) ? expf(lgv[i] - m) : 0.f;
        sum += pv[i];
    }
    for (int off = 32; off > 0; off >>= 1) sum += __shfl_xor(sum, off);
    const float inv = 1.0f / sum;

    float* __restrict__ bot = out + OFF_BOTP + (size_t)b * TPC;
    float tsel = 0.f;
    #pragma unroll
    for (int i = 0; i < 5; ++i) {
        const int t = lane + 64 * i;
        if (t < TPC) {
            const float p = pv[i] * inv;
            bot[t] = p;
            if (t == pb) tsel = p;
        }
    }
    for (int off = 32; off > 0; off >>= 1) tsel += __shfl_xor(tsel, off);

    if (lane == 0) {
        out[OFF_TGT + b]  = out[OFF_TOPP + (size_t)b * NC + c] * tsel;
        out[OFF_BIDX + b] = (float)mi;
        out[OFF_RIDX + b] = out[OFF_TIDX + b] * (float)TPC + (float)mi;
    }
}

// ------------- k_preds: outer product, 1 block per row -------------
// Lane owns fixed t (bp[t] in register); tp row in LDS, uniform broadcast
// read per c; coalesced contiguous store stream. ~5 instrs / 256B store.
__global__ __launch_bounds__(320) void k_preds(const float* __restrict__ out_ro,
                                               float* __restrict__ preds) {
    __shared__ float tps[NC];
    const int b = blockIdx.x;
    const int tid = threadIdx.x;

    const float* __restrict__ trow = out_ro + OFF_TOPP + (size_t)b * NC;
    const float* __restrict__ brow = out_ro + OFF_BOTP + (size_t)b * TPC;
    if (tid < NC) tps[tid] = trow[tid];
    float bpv = 0.f;
    if (tid < TPC) bpv = brow[tid];
    __syncthreads();

    if (tid >= TPC) return;
    float* __restrict__ p = preds + (size_t)b * ROWLEN + tid;
    #pragma unroll 4
    for (int c = 0; c < NC; ++c) {
        *p = tps[c] * bpv;
        p += TPC;
    }
}

// ------------- k_loss: deterministic single-block reduce -------------
__global__ __launch_bounds__(256) void k_loss(const float* __restrict__ out_ro,
                                              float* __restrict__ out) {
    __shared__ float red[4];
    const int tid = threadIdx.x;
    const float* __restrict__ target = out_ro + OFF_TGT;
    float s = 0.f;
    for (int i = tid; i < B; i += 256) s += logf(target[i]);
    for (int off = 32; off > 0; off >>= 1) s += __shfl_xor(s, off);
    if ((tid & 63) == 0) red[tid >> 6] = s;
    __syncthreads();
    if (tid == 0) {
        float tot = red[0] + red[1] + red[2] + red[3];
        out[OFF_LOSS] = -tot / (float)B;
    }
}

extern "C" void kernel_launch(void* const* d_in, const int* in_sizes, int n_in,
                              void* d_out, int out_size, void* d_ws, size_t ws_size,
                              hipStream_t stream) {
    const float* X      = (const float*)d_in[0];
    const int*   labels = (const int*)d_in[1];
    // d_in[2] = ntokens_per_class (scalar, hardcoded as TPC)
    const float* Wt = (const float*)d_in[3];
    const float* bt = (const float*)d_in[4];
    const float* Wb = (const float*)d_in[5];
    const float* bb = (const float*)d_in[6];
    float* out = (float*)d_out;
    float* scratch = out + OFF_PREDS;   // preds region doubles as scratch,
                                        // fully overwritten by k_preds later

    k_blogits<<<dim3(NC, KCH), dim3(320), 0, stream>>>(X, labels, Wb, scratch);
    k_top<<<dim3(B / K1_SB), dim3(320), 0, stream>>>(X, Wt, bt, out);
    k_bfinal<<<dim3(B / 4), dim3(256), 0, stream>>>(labels, bb, scratch, out);
    k_preds<<<dim3(B), dim3(320), 0, stream>>>(out, out + OFF_PREDS);
    k_loss<<<dim3(1), dim3(256), 0, stream>>>(out, out);
}

// Round 4
// 433.873 us; speedup vs baseline: 1.0459x; 1.0459x over previous
//
#include <hip/hip_runtime.h>
#include <hip/hip_bf16.h>
#include <cmath>

// Problem constants (fixed by setup_inputs)
#define B    2048
#define NH   512
#define NC   316
#define TPC  317
#define ROWLEN (NC * TPC)   // 100172

// d_out layout (flat float32, return-order concat)
#define OFF_LOSS    ((size_t)0)
#define OFF_TGT     ((size_t)1)
#define OFF_TOPP    ((size_t)(1 + B))
#define OFF_BOTP    (OFF_TOPP + (size_t)B * NC)
#define OFF_TIDX    (OFF_BOTP + (size_t)B * TPC)
#define OFF_BIDX    (OFF_TIDX + (size_t)B)
#define OFF_RIDX    (OFF_BIDX + (size_t)B)
#define OFF_PREDS   (OFF_RIDX + (size_t)B)
// NOTE: OFF_PREDS % 4 == 1 (float), ROWLEN % 4 == 0, TPC % 4 == 1.
// => global index of preds[b][c][t] ≡ 1 + c + t (mod 4); 16B-aligned iff
//    t ≡ (3 - c) & 3 (mod 4). k_preds exploits this.

// ---------------- k_top: [B,NH] x [NH,NC] + softmax/argmax ----------------
#define K1_SB 8

__global__ __launch_bounds__(320) void k_top(const float* __restrict__ X,
                                             const float* __restrict__ Wt,
                                             const float* __restrict__ bt,
                                             float* __restrict__ out) {
    __shared__ float xs[K1_SB][NH];   // 16 KB
    __shared__ float lg[K1_SB][NC];   // ~10 KB
    const int tid = threadIdx.x;
    const int b0 = blockIdx.x * K1_SB;

    for (int idx = tid; idx < K1_SB * NH; idx += 320) {
        xs[idx >> 9][idx & (NH - 1)] = X[(size_t)(b0 + (idx >> 9)) * NH + (idx & (NH - 1))];
    }
    __syncthreads();

    if (tid < NC) {
        float acc[K1_SB];
        #pragma unroll
        for (int s = 0; s < K1_SB; ++s) acc[s] = 0.f;
        #pragma unroll 2
        for (int k = 0; k < NH; k += 4) {
            const float w0 = Wt[(k + 0) * NC + tid];
            const float w1 = Wt[(k + 1) * NC + tid];
            const float w2 = Wt[(k + 2) * NC + tid];
            const float w3 = Wt[(k + 3) * NC + tid];
            #pragma unroll
            for (int s = 0; s < K1_SB; ++s) {
                const float4 x4 = *(const float4*)&xs[s][k];
                acc[s] += x4.x * w0 + x4.y * w1 + x4.z * w2 + x4.w * w3;
            }
        }
        const float bbv = bt[tid];
        #pragma unroll
        for (int s = 0; s < K1_SB; ++s) lg[s][tid] = acc[s] + bbv;
    }
    __syncthreads();

    const int wave = tid >> 6, lane = tid & 63;
    float* __restrict__ top_probs = out + OFF_TOPP;
    float* __restrict__ top_indx  = out + OFF_TIDX;

    for (int s = wave; s < K1_SB; s += 5) {
        const int b = b0 + s;
        float m = -INFINITY; int mi = 0;
        for (int c = lane; c < NC; c += 64) {
            float v = lg[s][c];
            if (v > m) { m = v; mi = c; }
        }
        for (int off = 32; off > 0; off >>= 1) {
            float om = __shfl_xor(m, off);
            int omi  = __shfl_xor(mi, off);
            if (om > m || (om == m && omi < mi)) { m = om; mi = omi; }
        }
        float sum = 0.f;
        for (int c = lane; c < NC; c += 64) sum += expf(lg[s][c] - m);
        for (int off = 32; off > 0; off >>= 1) sum += __shfl_xor(sum, off);
        const float inv = 1.0f / sum;
        for (int c = lane; c < NC; c += 64)
            top_probs[(size_t)b * NC + c] = expf(lg[s][c] - m) * inv;
        if (lane == 0) top_indx[b] = (float)mi;
    }
}

// ------------- k_blogits: partial bottom logits, grid (NC, KCH) -------------
#define KCH     8
#define KLEN    (NH / KCH)    // 64
#define SG      8
#define SCR_PAD 320

__global__ __launch_bounds__(320) void k_blogits(const float* __restrict__ X,
                                                 const int* __restrict__ labels,
                                                 const float* __restrict__ Wb,
                                                 float* __restrict__ scratch) {
    __shared__ int   list[B];          // 8 KB
    __shared__ float xs[SG][KLEN];     // 2 KB
    __shared__ int   cnt;

    const int tid = threadIdx.x;
    const int c   = blockIdx.x;
    const int kc  = blockIdx.y;
    if (tid == 0) cnt = 0;
    __syncthreads();

    for (int i = tid; i < B; i += 320) {
        int lab = labels[i];
        if (lab / TPC == c) list[atomicAdd(&cnt, 1)] = i;
    }
    __syncthreads();
    const int n = cnt;
    if (n == 0) return;

    const float* __restrict__ Wc = Wb + (size_t)c * NH * TPC + (size_t)kc * KLEN * TPC;
    const float* __restrict__ Xc = X + kc * KLEN;

    for (int start = 0; start < n; start += SG) {
        const int ns = min(SG, n - start);
        __syncthreads();
        for (int idx = tid; idx < ns * KLEN; idx += 320) {
            xs[idx >> 6][idx & (KLEN - 1)] =
                Xc[(size_t)list[start + (idx >> 6)] * NH + (idx & (KLEN - 1))];
        }
        __syncthreads();

        if (tid < TPC) {
            float acc[SG];
            #pragma unroll
            for (int s = 0; s < SG; ++s) acc[s] = 0.f;
            #pragma unroll 2
            for (int k = 0; k < KLEN; k += 4) {
                const float w0 = Wc[(size_t)(k + 0) * TPC + tid];
                const float w1 = Wc[(size_t)(k + 1) * TPC + tid];
                const float w2 = Wc[(size_t)(k + 2) * TPC + tid];
                const float w3 = Wc[(size_t)(k + 3) * TPC + tid];
                #pragma unroll
                for (int s = 0; s < SG; ++s) {
                    const float4 x4 = *(const float4*)&xs[s][k];
                    acc[s] += x4.x * w0 + x4.y * w1 + x4.z * w2 + x4.w * w3;
                }
            }
            for (int s = 0; s < ns; ++s)
                scratch[((size_t)list[start + s] * KCH + kc) * SCR_PAD + tid] = acc[s];
        }
    }
}

// ------------- k_bfinal: reduce partials + bias, softmax, outputs -------------
__global__ __launch_bounds__(256) void k_bfinal(const int* __restrict__ labels,
                                                const float* __restrict__ bbias,
                                                const float* __restrict__ scratch,
                                                float* __restrict__ out) {
    const int tid  = threadIdx.x;
    const int lane = tid & 63;
    const int b    = blockIdx.x * 4 + (tid >> 6);

    const int lab = labels[b];
    const int c   = lab / TPC;
    const int pb  = lab - c * TPC;

    float lgv[5];
    #pragma unroll
    for (int i = 0; i < 5; ++i) {
        const int t = lane + 64 * i;
        float v = -INFINITY;
        if (t < TPC) {
            v = bbias[(size_t)c * TPC + t];
            #pragma unroll
            for (int kc = 0; kc < KCH; ++kc)
                v += scratch[((size_t)b * KCH + kc) * SCR_PAD + t];
        }
        lgv[i] = v;
    }

    float m = -INFINITY; int mi = 0;
    #pragma unroll
    for (int i = 0; i < 5; ++i) {
        const int t = lane + 64 * i;
        if (lgv[i] > m) { m = lgv[i]; mi = t; }
    }
    for (int off = 32; off > 0; off >>= 1) {
        float om = __shfl_xor(m, off);
        int omi  = __shfl_xor(mi, off);
        if (om > m || (om == m && omi < mi)) { m = om; mi = omi; }
    }

    float pv[5];
    float sum = 0.f;
    #pragma unroll
    for (int i = 0; i < 5; ++i) {
        const int t = lane + 64 * i;
        pv[i] = (t < TPC) ? expf(lgv[i] - m) : 0.f;
        sum += pv[i];
    }
    for (int off = 32; off > 0; off >>= 1) sum += __shfl_xor(sum, off);
    const float inv = 1.0f / sum;

    float* __restrict__ bot = out + OFF_BOTP + (size_t)b * TPC;
    float tsel = 0.f;
    #pragma unroll
    for (int i = 0; i < 5; ++i) {
        const int t = lane + 64 * i;
        if (t < TPC) {
            const float p = pv[i] * inv;
            bot[t] = p;
            if (t == pb) tsel = p;
        }
    }
    for (int off = 32; off > 0; off >>= 1) tsel += __shfl_xor(tsel, off);

    if (lane == 0) {
        out[OFF_TGT + b]  = out[OFF_TOPP + (size_t)b * NC + c] * tsel;
        out[OFF_BIDX + b] = (float)mi;
        out[OFF_RIDX + b] = out[OFF_TIDX + b] * (float)TPC + (float)mi;
    }
}

// ------------- k_preds v4: aligned dwordx4 outer-product stream -------------
// Wave cg handles classes c ≡ cg (mod 4); alignment shift S = (3-cg)&3 is
// wave-constant, so bp quads come from statically-indexed registers and every
// main store is an aligned global_store_dwordx4 (full-line coverage).
// Per c: quads at t = S+4*l, l in [0, Q_S);  Q_S = {79,79,78,78} for S={0,1,2,3}.
// Lanes 0..63 cover l=0..63; lanes < QHI cover l=64..Q_S-1 (QHI = Q_S-64).
// Leftover 12 elems per 4-class cycle (948/row) via scalar cleanup pass.
__global__ __launch_bounds__(256) void k_preds(const float* __restrict__ out_ro,
                                               float* __restrict__ preds) {
    __shared__ float tps[NC];
    __shared__ __align__(16) float bps[328];   // 317 real + zero pad
    const int tid  = threadIdx.x;
    const int b    = blockIdx.x;
    const int cg   = tid >> 6;    // wave index = class-group (c mod 4)
    const int lane = tid & 63;

    const float* __restrict__ trow = out_ro + OFF_TOPP + (size_t)b * NC;
    const float* __restrict__ brow = out_ro + OFF_BOTP + (size_t)b * TPC;
    for (int i = tid; i < NC; i += 256) tps[i] = trow[i];
    for (int i = tid; i < 328; i += 256) bps[i] = (i < TPC) ? brow[i] : 0.f;
    __syncthreads();

    float* const row = preds + (size_t)b * ROWLEN;

    // lane-owned bp windows, statically indexed after the S-switch
    const float4 la = *(const float4*)&bps[4 * lane];
    const float4 lb = *(const float4*)&bps[4 * lane + 4];
    float4 ha = make_float4(0.f, 0.f, 0.f, 0.f), hb = ha;
    if (lane < 16) {
        ha = *(const float4*)&bps[256 + 4 * lane];
        hb = *(const float4*)&bps[256 + 4 * lane + 4];
    }
    const float lo[8] = {la.x, la.y, la.z, la.w, lb.x, lb.y, lb.z, lb.w};
    const float hi[8] = {ha.x, ha.y, ha.z, ha.w, hb.x, hb.y, hb.z, hb.w};

#define RUN_MAIN(S, QHI)                                                    \
    {                                                                       \
        const float e0 = lo[S], e1 = lo[(S)+1], e2 = lo[(S)+2], e3 = lo[(S)+3]; \
        float* p = row + cg * TPC + (S) + 4 * lane;                         \
        _Pragma("unroll 2")                                                 \
        for (int c = cg; c < NC; c += 4) {                                  \
            const float tv = tps[c];                                        \
            *(float4*)p = make_float4(e0*tv, e1*tv, e2*tv, e3*tv);          \
            p += 4 * TPC;                                                   \
        }                                                                   \
        if (lane < (QHI)) {                                                 \
            const float f0 = hi[S], f1 = hi[(S)+1], f2 = hi[(S)+2], f3 = hi[(S)+3]; \
            float* p2 = row + cg * TPC + (S) + 4 * (lane + 64);             \
            _Pragma("unroll 2")                                             \
            for (int c = cg; c < NC; c += 4) {                              \
                const float tv = tps[c];                                    \
                *(float4*)p2 = make_float4(f0*tv, f1*tv, f2*tv, f3*tv);     \
                p2 += 4 * TPC;                                              \
            }                                                               \
        }                                                                   \
    }

    if      (cg == 0) RUN_MAIN(3, 14)
    else if (cg == 1) RUN_MAIN(2, 14)
    else if (cg == 2) RUN_MAIN(1, 15)
    else              RUN_MAIN(0, 15)
#undef RUN_MAIN

    // Edge cleanup: per 4-class cycle, 12 leftover (c,t):
    //  c%4==0 (S=3): t in {0,1,2,315,316}; c%4==1 (S=2): {0,1,314,315,316};
    //  c%4==2 (S=1): {0};                  c%4==3 (S=0): {316}.
    for (int idx = tid; idx < 79 * 12; idx += 256) {
        const int cyc = idx / 12;
        const int r   = idx - cyc * 12;
        int dc, dt;
        if (r < 5)        { dc = 0; dt = (r < 3) ? r : 312 + r; }
        else if (r < 10)  { const int r2 = r - 5; dc = 1; dt = (r2 < 2) ? r2 : 312 + r2; }
        else if (r == 10) { dc = 2; dt = 0; }
        else              { dc = 3; dt = 316; }
        const int c = 4 * cyc + dc;
        row[c * TPC + dt] = tps[c] * bps[dt];
    }
}

// ------------- k_loss: deterministic single-block reduce -------------
__global__ __launch_bounds__(256) void k_loss(const float* __restrict__ out_ro,
                                              float* __restrict__ out) {
    __shared__ float red[4];
    const int tid = threadIdx.x;
    const float* __restrict__ target = out_ro + OFF_TGT;
    float s = 0.f;
    for (int i = tid; i < B; i += 256) s += logf(target[i]);
    for (int off = 32; off > 0; off >>= 1) s += __shfl_xor(s, off);
    if ((tid & 63) == 0) red[tid >> 6] = s;
    __syncthreads();
    if (tid == 0) {
        float tot = red[0] + red[1] + red[2] + red[3];
        out[OFF_LOSS] = -tot / (float)B;
    }
}

extern "C" void kernel_launch(void* const* d_in, const int* in_sizes, int n_in,
                              void* d_out, int out_size, void* d_ws, size_t ws_size,
                              hipStream_t stream) {
    const float* X      = (const float*)d_in[0];
    const int*   labels = (const int*)d_in[1];
    // d_in[2] = ntokens_per_class (scalar, hardcoded as TPC)
    const float* Wt = (const float*)d_in[3];
    const float* bt = (const float*)d_in[4];
    const float* Wb = (const float*)d_in[5];
    const float* bb = (const float*)d_in[6];
    float* out = (float*)d_out;
    float* scratch = out + OFF_PREDS;   // preds region doubles as scratch,
                                        // fully overwritten by k_preds later

    k_blogits<<<dim3(NC, KCH), dim3(320), 0, stream>>>(X, labels, Wb, scratch);
    k_top<<<dim3(B / K1_SB), dim3(320), 0, stream>>>(X, Wt, bt, out);
    k_bfinal<<<dim3(B / 4), dim3(256), 0, stream>>>(labels, bb, scratch, out);
    k_preds<<<dim3(B), dim3(256), 0, stream>>>(out, out + OFF_PREDS);
    k_loss<<<dim3(1), dim3(256), 0, stream>>>(out, out);
}